// Round 18
// baseline (67.425 us; speedup 1.0000x reference)
//
#include <hip/hip_runtime.h>
#include <hip/hip_bf16.h>
#include <math.h>

#define BN 8
#define TT 128
#define DD 400
#define HH 300
#define LL 45
#define SS 129          // T+1 head candidates

// ---------------- Kernel A: projections (v9, R17) -------------------------
// grid = 256 x 640 (10 waves, K-split 2x200). Root row folded into block 128
// as a 9th row. Also zeroes accum + ticket for the fused second kernel.
__global__ __launch_bounds__(640) void proj_kernel(
    const float* __restrict__ cont, const float* __restrict__ root,
    const float* __restrict__ W1a, const float* __restrict__ W1b,
    const float* __restrict__ b1,
    const int* __restrict__ slen,
    float* __restrict__ AP, float* __restrict__ BPX,
    float* __restrict__ accum, int* __restrict__ ticket)
{
    __shared__ float rows_s[9 * DD];   // 14.4 KB; re-used as combine buffer
    const int blk = blockIdx.x;        // 0..255
    const int tid = threadIdx.x;

    const bool isA   = (blk < 128);
    const bool isRB  = (blk == 128);   // root block (B-side, never skips)
    const int  u     = isA ? blk : blk - 128;
    const int  row0  = u * 8;

    if (isRB && tid == 0) { accum[0] = 0.f; ticket[0] = 0; }
    if (isA && ((row0 & 127) >= slen[row0 >> 7])) return;  // masked AP rows

    {   // stage 8 cont rows + root row (branch-free)
        const float* src = cont + (size_t)row0 * DD;
        for (int i = tid; i < 8 * DD; i += 640) rows_s[i] = src[i];
        for (int i = tid; i < DD; i += 640)     rows_s[8 * DD + i] = root[i];
    }
    __syncthreads();

    const int grp = tid / 320;         // wave-aligned K-group
    const int h   = tid % 320;
    const bool hok = (h < HH);

    float acc[9];
    #pragma unroll
    for (int r = 0; r < 9; ++r) acc[r] = 0.f;

    if (hok) {
        const float* wp = (isA ? W1a : W1b) + (size_t)(grp * 200) * HH + h;
        const float* rs = rows_s;
        const int dbase = grp * 200;
        #pragma unroll
        for (int dc = 0; dc < 200; dc += 4) {
            const float w0 = wp[(size_t)(dc + 0) * HH];
            const float w1 = wp[(size_t)(dc + 1) * HH];
            const float w2 = wp[(size_t)(dc + 2) * HH];
            const float w3 = wp[(size_t)(dc + 3) * HH];
            #pragma unroll
            for (int r = 0; r < 9; ++r) {
                const float4 ra = *(const float4*)&rs[r * DD + dbase + dc];
                acc[r] = fmaf(ra.x, w0, acc[r]);
                acc[r] = fmaf(ra.y, w1, acc[r]);
                acc[r] = fmaf(ra.z, w2, acc[r]);
                acc[r] = fmaf(ra.w, w3, acc[r]);
            }
        }
    }

    __syncthreads();                   // rows_s reads done; safe to alias
    float* red = rows_s;               // [320][9] = 2880 floats
    if (grp == 1 && hok) {
        #pragma unroll
        for (int r = 0; r < 9; ++r) red[h * 9 + r] = acc[r];
    }
    __syncthreads();
    if (grp == 0 && hok) {
        float tot[9];
        #pragma unroll
        for (int r = 0; r < 9; ++r) tot[r] = acc[r] + red[h * 9 + r];
        if (isA) {
            const float bb = b1[h];
            float* dst = AP + (size_t)row0 * HH + h;
            #pragma unroll
            for (int r = 0; r < 8; ++r) dst[(size_t)r * HH] = tot[r] + bb;
        } else {
            const int b = row0 >> 7, t = row0 & 127;
            float* dst = BPX + ((size_t)(b * SS + t + 1)) * HH + h;
            #pragma unroll
            for (int r = 0; r < 8; ++r) dst[(size_t)r * HH] = tot[r];
            if (isRB) {
                #pragma unroll
                for (int bb2 = 0; bb2 < BN; ++bb2)
                    BPX[(size_t)bb2 * SS * HH + h] = tot[8];
            }
        }
    }
}

// ---------------- Kernel B: fused arc + softmax + CE + label + finalize ---
// grid = 256 = b*32 + tg (4 t per block), block = 256 (4 waves).
// Phase A: arc logits for 4 t x all 129 s — BPX streamed via LDS in 16-row
//   chunks; thread = (t=tid&3, s=(tid>>2)&15, h-quarter=tid>>6); partials
//   combined in LDS. Logits stay in LDS -> no arc->smx kernel boundary.
// Phase B: per-wave 129-way log-softmax/argmax/CE (wave w owns t0+w).
// Phase C: wave-private selh + 45-way label GEMV + CE, one atomicAdd.
// Phase D: every block ticks; ticket #255 computes the final mean.
__global__ __launch_bounds__(256) void arcsmx_kernel(
    const float* __restrict__ AP, const float* __restrict__ BPX,
    const float* __restrict__ Wa, const float* __restrict__ Wl,
    const float* __restrict__ bl,
    const int* __restrict__ slen, const int* __restrict__ darc,
    const int* __restrict__ dlab, const int* __restrict__ used,
    float* __restrict__ accum, int* __restrict__ ticket,
    float* __restrict__ out)
{
    __shared__ float ap_s[4][HH];
    __shared__ float wa_s[HH];
    __shared__ float bp_s[16][HH];
    __shared__ float lg_s[4][132];
    __shared__ float part_s[64][5];
    __shared__ float selh[4][HH];

    const int blk = blockIdx.x;
    const int b  = blk >> 5;
    const int tg = blk & 31;
    const int t0 = tg * 4;
    const int tid  = threadIdx.x;
    const int lane = tid & 63;
    const int wv   = tid >> 6;
    const int len  = slen[b];

    if (t0 < len) {
        {   // stage AP rows + Wa
            const float* apg = AP + (size_t)(b * TT + t0) * HH;
            for (int i = tid; i < 4 * HH; i += 256) ap_s[i / HH][i % HH] = apg[i];
            for (int i = tid; i < HH; i += 256)     wa_s[i] = Wa[i];
        }
        __syncthreads();

        // ---- Phase A: logits over 9 chunks of 16 s (last chunk = s 128) ----
        const int tl = tid & 3;
        const int sl = (tid >> 2) & 15;
        const int qq = tid >> 6;               // h-quarter (== wv)
        const int h0 = qq * 76;
        const int hn = (qq == 3) ? 72 : 76;

        for (int c = 0; c < 9; ++c) {
            const int s0 = c * 16;
            const int nrows = (c == 8) ? 1 : 16;
            const float* bpg = BPX + ((size_t)b * SS + s0) * HH;
            for (int i = tid; i < nrows * HH; i += 256)
                bp_s[i / HH][i % HH] = bpg[i];
            __syncthreads();

            float p = 0.f;
            if (sl < nrows) {
                const float* ar = ap_s[tl];
                const float* br = bp_s[sl];
                for (int hh = h0; hh < h0 + hn; hh += 4) {
                    const float4 a4 = *(const float4*)&ar[hh];
                    const float4 b4 = *(const float4*)&br[hh];
                    const float4 w4 = *(const float4*)&wa_s[hh];
                    p = fmaf(fmaxf(a4.x + b4.x, 0.f), w4.x, p);
                    p = fmaf(fmaxf(a4.y + b4.y, 0.f), w4.y, p);
                    p = fmaf(fmaxf(a4.z + b4.z, 0.f), w4.z, p);
                    p = fmaf(fmaxf(a4.w + b4.w, 0.f), w4.w, p);
                }
            }
            part_s[tid & 63][qq] = p;
            __syncthreads();
            if (qq == 0 && sl < nrows) {
                const int pid = tid & 63;
                lg_s[tl][s0 + sl] = part_s[pid][0] + part_s[pid][1]
                                  + part_s[pid][2] + part_s[pid][3];
            }
            __syncthreads();                    // bp_s/part_s reuse next chunk
        }

        // ---- Phases B+C: per-wave softmax + CE + label (t = t0 + wv) ----
        const int t = t0 + wv;
        if (t < len) {
            const float* lg = lg_s[wv];
            const float v0 = lg[lane];
            const float v1 = lg[64 + lane];
            const float v2 = (lane == 0) ? lg[128] : -INFINITY;

            float m = fmaxf(fmaxf(v0, v1), v2);
            #pragma unroll
            for (int off = 32; off; off >>= 1) m = fmaxf(m, __shfl_xor(m, off, 64));
            float e = __expf(v0 - m) + __expf(v1 - m) + ((lane == 0) ? __expf(v2 - m) : 0.f);
            #pragma unroll
            for (int off = 32; off; off >>= 1) e += __shfl_xor(e, off, 64);
            const float arc_lse = m + __logf(e);

            float bv = v0; int bi = lane;
            if (v1 > bv) { bv = v1; bi = 64 + lane; }
            if (lane == 0 && v2 > bv) { bv = v2; bi = 128; }
            #pragma unroll
            for (int off = 32; off; off >>= 1) {
                const float ov = __shfl_xor(bv, off, 64);
                const int   oi = __shfl_xor(bi, off, 64);
                if (ov > bv || (ov == bv && oi < bi)) { bv = ov; bi = oi; }
            }
            const int da = darc[b * TT + t];
            const float arc_ce = arc_lse - lg[da];
            const int sel = used[0] ? da : bi;

            // wave-private selected pair representation
            const float* bp = BPX + ((size_t)b * SS + sel) * HH;
            for (int hh = lane; hh < HH; hh += 64)
                selh[wv][hh] = fmaxf(ap_s[wv][hh] + bp[hh], 0.f);

            // label GEMV: lane l < 45 owns label l (selh broadcast reads)
            float a0 = 0.f, a1 = 0.f;
            if (lane < LL) {
                a0 = bl[lane];
                for (int hh = 0; hh < HH; hh += 4) {
                    a0 = fmaf(selh[wv][hh + 0], Wl[(hh + 0) * LL + lane], a0);
                    a1 = fmaf(selh[wv][hh + 1], Wl[(hh + 1) * LL + lane], a1);
                    a0 = fmaf(selh[wv][hh + 2], Wl[(hh + 2) * LL + lane], a0);
                    a1 = fmaf(selh[wv][hh + 3], Wl[(hh + 3) * LL + lane], a1);
                }
            }
            const float a = (lane < LL) ? (a0 + a1) : -INFINITY;
            float lm = a;
            #pragma unroll
            for (int off = 32; off; off >>= 1) lm = fmaxf(lm, __shfl_xor(lm, off, 64));
            float le = (lane < LL) ? __expf(a - lm) : 0.f;
            #pragma unroll
            for (int off = 32; off; off >>= 1) le += __shfl_xor(le, off, 64);
            const float lab_lse = lm + __logf(le);

            const int dl = dlab[b * TT + t];
            const float adl = __shfl(a, dl, 64);
            if (lane == 0)
                atomicAdd(accum, arc_ce + (lab_lse - adl));
        }
    }

    // ---- Phase D: ticket finalize (every block participates) ----
    __syncthreads();
    if (tid == 0) {
        __threadfence();
        if (atomicAdd(ticket, 1) == 255) {
            int n = 0;
            #pragma unroll
            for (int bb = 0; bb < BN; ++bb) {
                int l = slen[bb]; l = l < 0 ? 0 : (l > TT ? TT : l); n += l;
            }
            float nv = (float)n; if (nv < 1.f) nv = 1.f;
            const float total = atomicAdd(accum, 0.f);   // coherent read
            out[0] = total / (2.f * nv);
        }
    }
}

extern "C" void kernel_launch(void* const* d_in, const int* in_sizes, int n_in,
                              void* d_out, int out_size, void* d_ws, size_t ws_size,
                              hipStream_t stream) {
    const float* cont = (const float*)d_in[0];
    const float* root = (const float*)d_in[1];
    const float* W1a  = (const float*)d_in[2];
    const float* W1b  = (const float*)d_in[3];
    const float* b1   = (const float*)d_in[4];
    const float* Wa   = (const float*)d_in[5];
    // d_in[6] = ba: cancels in CE and argmax -> unused
    const float* Wl   = (const float*)d_in[7];
    const float* bl   = (const float*)d_in[8];
    const int* slen   = (const int*)d_in[9];
    const int* darc   = (const int*)d_in[10];
    const int* dlab   = (const int*)d_in[11];
    const int* used   = (const int*)d_in[12];
    float* out = (float*)d_out;

    float* AP     = (float*)d_ws;             // 1024*300
    float* BPX    = AP + 1024 * HH;           // 8*129*300
    float* accum  = BPX + BN * SS * HH;       // 1 float
    int*   ticket = (int*)(accum + 16);       // 1 int (aligned past accum)

    proj_kernel<<<256, 640, 0, stream>>>(cont, root, W1a, W1b, b1, slen,
                                         AP, BPX, accum, ticket);
    arcsmx_kernel<<<256, 256, 0, stream>>>(AP, BPX, Wa, Wl, bl, slen,
                                           darc, dlab, used, accum, ticket, out);
}